// Round 1
// baseline (530.932 us; speedup 1.0000x reference)
//
#include <hip/hip_runtime.h>
#include <stdint.h>

#define C_ITEMS 16384
#define NCLS 16
#define HSTRIDE 16386   // hist entries per class (opt in [1, P+1], P <= 16384)

// ---- workspace layout (bytes) ----
static const size_t OFF_COL  = 0;                                   // 16*16384 f32 column-major scores
static const size_t OFF_SPOS = 1u << 20;                            // sorted positives (desc) per class
static const size_t OFF_RANK = 2u << 20;                            // per-(class,item) neg rank (u32)
static const size_t OFF_HIST = 3u << 20;                            // 16 * HSTRIDE u32
static const size_t OFF_CNT  = OFF_HIST + (size_t)NCLS * HSTRIDE * 4; // 16 u32 P-counts
static const size_t OFF_ACCS = OFF_CNT + 64;                        // 16 double: sum (P+2-2opt)*sm
static const size_t OFF_ACCV = OFF_ACCS + 128;                      // 16 double: sum sm
static const size_t OFF_TOT  = OFF_ACCV + 128;                      // 1 double total
static const size_t ZERO_BYTES = OFF_TOT + 8 - OFF_RANK;            // zero rank..total

__device__ __forceinline__ unsigned ordkey(float f) {
  unsigned b = __float_as_uint(f);
  return (b & 0x80000000u) ? ~b : (b | 0x80000000u);   // monotone float->uint
}

__global__ void k_zero(unsigned* p, int n) {
  int stride = gridDim.x * blockDim.x;
  for (int t = blockIdx.x * blockDim.x + threadIdx.x; t < n; t += stride) p[t] = 0u;
}

__global__ void k_transpose(const float* __restrict__ scores, float* __restrict__ col) {
  int t = blockIdx.x * 256 + threadIdx.x;      // 0..262143
  float v = scores[t];
  int i = t >> 4, c = t & 15;
  col[(c << 14) | i] = v;
}

__global__ void k_counts(const int* __restrict__ labels, unsigned* __restrict__ counts) {
  __shared__ unsigned lc[NCLS];
  int tid = threadIdx.x;
  if (tid < NCLS) lc[tid] = 0;
  __syncthreads();
  int m = blockIdx.x * 256 + tid;
  atomicAdd(&lc[labels[m] & 15], 1u);
  __syncthreads();
  if (tid < NCLS && lc[tid]) atomicAdd(&counts[tid], lc[tid]);
}

// ---- positives: rank among positives (descending, stable) + scatter sorted array ----
#define PCAP 4096
__global__ void k_posrank(const float* __restrict__ col, const int* __restrict__ labels,
                          float* __restrict__ spos) {
  int c = blockIdx.x;
  int tid = threadIdx.x;
  const float* cs = col + (c << 14);
  __shared__ unsigned pc;
  __shared__ unsigned long long pk[PCAP];
  if (tid == 0) pc = 0;
  __syncthreads();
  for (int m = tid; m < C_ITEMS; m += 256) {
    if (labels[m] == c) {
      unsigned idx = atomicAdd(&pc, 1u);
      if (idx < PCAP)
        pk[idx] = ((unsigned long long)(~ordkey(cs[m])) << 32) | (unsigned)m;
    }
  }
  __syncthreads();
  unsigned P = pc;
  if (P <= PCAP) {
    for (unsigned q = tid; q < P; q += 256) {
      unsigned long long k64 = pk[q];
      unsigned cq = 0;
      for (unsigned t = 0; t < P; ++t) cq += (pk[t] < k64) ? 1u : 0u;
      unsigned i = (unsigned)(k64 & 0xFFFFFFFFu);
      spos[(c << 14) + cq] = cs[i];
    }
  } else { // safety fallback (won't trigger for this input)
    for (int m = tid; m < C_ITEMS; m += 256) {
      if (labels[m] != c) continue;
      unsigned long long k64 = ((unsigned long long)(~ordkey(cs[m])) << 32) | (unsigned)m;
      unsigned cq = 0;
      for (int t = 0; t < C_ITEMS; ++t) {
        if (labels[t] == c) {
          unsigned long long o = ((unsigned long long)(~ordkey(cs[t])) << 32) | (unsigned)t;
          cq += (o < k64) ? 1u : 0u;
        }
      }
      spos[(c << 14) + cq] = cs[m];
    }
  }
}

// ---- negatives: O(N^2) stable ascending rank via 64-bit (key,idx) counting ----
#define NR_TILE 1024
__global__ void k_negrank(const float* __restrict__ col, const int* __restrict__ labels,
                          unsigned* __restrict__ rank) {
  int c = blockIdx.y;
  int tid = threadIdx.x;
  const float* cs = col + (c << 14);
  int item0 = blockIdx.x * 2048 + tid;   // 8 items per thread: item0 + r*256
  int mbase = blockIdx.z * 2048;         // 8 m-slices
  __shared__ unsigned long long tile[NR_TILE];
  unsigned long long myk[8];
  unsigned cnt[8];
  unsigned negmask = 0;
#pragma unroll
  for (int r = 0; r < 8; ++r) {
    int i = item0 + (r << 8);
    unsigned k = ordkey(cs[i]);
    if (labels[i] != c) negmask |= (1u << r);
    myk[r] = ((unsigned long long)k << 32) | (unsigned)i;
    cnt[r] = 0;
  }
  for (int tb = 0; tb < 2048; tb += NR_TILE) {
    for (int q = tid; q < NR_TILE; q += 256) {
      int m = mbase + tb + q;
      unsigned k = ordkey(cs[m]);
      tile[q] = (labels[m] != c) ? (((unsigned long long)k << 32) | (unsigned)m)
                                 : 0xFFFFFFFFFFFFFFFFull; // positives never counted
    }
    __syncthreads();
#pragma unroll 4
    for (int q = 0; q < NR_TILE; ++q) {
      unsigned long long tv = tile[q];
#pragma unroll
      for (int r = 0; r < 8; ++r) cnt[r] += (tv < myk[r]) ? 1u : 0u;
    }
    __syncthreads();
  }
#pragma unroll
  for (int r = 0; r < 8; ++r)
    if (negmask & (1u << r))
      atomicAdd(&rank[(c << 14) + item0 + (r << 8)], cnt[r]);
}

// ---- per-negative suffix-scan argmax (opt_j), histogram, minus-side sums ----
#define OTILE 2048
#define HCAP 4096
__global__ void k_opt(const float* __restrict__ col, const int* __restrict__ labels,
                      const unsigned* __restrict__ counts, const float* __restrict__ spos,
                      const unsigned* __restrict__ rank, unsigned* __restrict__ hist,
                      double* __restrict__ accS, double* __restrict__ accV) {
  int c = blockIdx.y;
  int P = (int)counts[c];
  int N = C_ITEMS - P;
  if (P == 0 || N == 0) return;
  int tid = threadIdx.x;
  int i = blockIdx.x * 256 + tid;
  __shared__ float sp[OTILE];
  __shared__ unsigned lh[HCAP];
  __shared__ double red[256];
  bool active = (labels[i] != c);
  float v = col[(c << 14) + i];
  unsigned j0 = active ? rank[(c << 14) + i] : 0u;  // ascending rank, 0-based
  float invP = 1.0f / (float)P;
  float coef = 2.0f / ((float)P * (float)N);
  float a = coef * v;                               // delta = invP*rcp(j+k) - coef*sp + a
  float fcnt = (float)(j0 + (unsigned)P + 1u);      // j+k at k=P (j = j0+1); exact in f32
  float s = 0.0f, best = 0.0f;                      // suffix at i=P is 0
  int besti = P;
  int nchunks = (P + OTILE - 1) / OTILE;
  for (int cb = nchunks - 1; cb >= 0; --cb) {
    int base = cb * OTILE;
    int len = min(OTILE, P - base);
    __syncthreads();
    for (int t = tid; t < len; t += 256) sp[t] = spos[(c << 14) + base + t];
    __syncthreads();
    if (active) {
      for (int q = len - 1; q >= 0; --q) {
        float spv = sp[q];
        float r = __builtin_amdgcn_rcpf(fcnt);
        float delta = fmaf(invP, r, fmaf(-coef, spv, a));
        s += delta;
        if (s >= best) { best = s; besti = base + q; }  // >= : first-max-on-tie
        fcnt -= 1.0f;
      }
    }
  }
  int opt = besti + 1;  // 1..P+1
  if (P + 2 <= HCAP) {  // block-local histogram to avoid hot global atomics
    __syncthreads();
    for (int t = tid; t < P + 2; t += 256) lh[t] = 0u;
    __syncthreads();
    if (active) atomicAdd(&lh[opt], 1u);
    __syncthreads();
    for (int t = tid; t < P + 2; t += 256)
      if (lh[t]) atomicAdd(&hist[c * HSTRIDE + t], lh[t]);
  } else {
    if (active) atomicAdd(&hist[c * HSTRIDE + opt], 1u);
  }
  double cm = active ? (double)(P + 2 - 2 * opt) * (double)v : 0.0;
  double sv = active ? (double)v : 0.0;
  red[tid] = cm; __syncthreads();
  for (int sh = 128; sh > 0; sh >>= 1) { if (tid < sh) red[tid] += red[tid + sh]; __syncthreads(); }
  if (tid == 0) atomicAdd(&accS[c], red[0]);
  __syncthreads();
  red[tid] = sv; __syncthreads();
  for (int sh = 128; sh > 0; sh >>= 1) { if (tid < sh) red[tid] += red[tid + sh]; __syncthreads(); }
  if (tid == 0) atomicAdd(&accV[c], red[0]);
}

// ---- per-class: prefix-sum hist -> r_plus, the three plus-side sums, loss ----
__global__ void k_finalize(const unsigned* __restrict__ counts, const unsigned* __restrict__ hist,
                           const float* __restrict__ spos, const double* __restrict__ accS,
                           const double* __restrict__ accV, double* __restrict__ total) {
  int c = blockIdx.x;
  int tid = threadIdx.x;
  int P = (int)counts[c];
  int N = C_ITEMS - P;
  if (P == 0 || N == 0) return;
  __shared__ unsigned sc[256];
  __shared__ double red[256];
  const unsigned* h = hist + c * HSTRIDE;
  int M = P + 1;                       // o in [1, P+1]
  int L = (M + 255) / 256;
  int o0 = 1 + tid * L;
  int o1 = min(o0 + L, P + 2);
  unsigned part = 0;
  for (int o = o0; o < o1; ++o) part += h[o];
  sc[tid] = part;
  __syncthreads();
  if (tid == 0) {
    unsigned runp = 0;
    for (int t = 0; t < 256; ++t) { unsigned tmp = sc[t]; sc[t] = runp; runp += tmp; }
  }
  __syncthreads();
  unsigned run = sc[tid];
  double a1 = 0.0, a2 = 0.0, a3 = 0.0;
  for (int o = o0; o < o1; ++o) {
    run += h[o];                       // inclusive cum over [1..o]
    if (o <= P) {
      int k0 = o - 1;
      double rp = 1.0 + (double)run;   // r_plus[k0] = 1 + cum[k0+1]
      double spv = (double)spos[(c << 14) + k0];
      a1 += (double)(k0 + 1) / ((double)k0 + rp);
      a2 += spv * ((double)N + 2.0 - 2.0 * rp);
      a3 += spv;
    }
  }
  red[tid] = a1; __syncthreads();
  for (int s = 128; s > 0; s >>= 1) { if (tid < s) red[tid] += red[tid + s]; __syncthreads(); }
  double r1 = red[0]; __syncthreads();
  red[tid] = a2; __syncthreads();
  for (int s = 128; s > 0; s >>= 1) { if (tid < s) red[tid] += red[tid + s]; __syncthreads(); }
  double r2 = red[0]; __syncthreads();
  red[tid] = a3; __syncthreads();
  for (int s = 128; s > 0; s >>= 1) { if (tid < s) red[tid] += red[tid + s]; __syncthreads(); }
  double r3 = red[0];
  if (tid == 0) {
    double Pd = (double)P, Nd = (double)N;
    double FR  = r2 + accS[c];
    double FRs = Nd * r3 - Pd * accV[c];
    double lc  = (1.0 - r1 / Pd) + (FR - FRs) / (Pd * Nd);
    atomicAdd(total, lc);
  }
}

__global__ void k_out(const double* __restrict__ total, float* __restrict__ out) {
  out[0] = (float)(total[0] / (double)NCLS);
}

extern "C" void kernel_launch(void* const* d_in, const int* in_sizes, int n_in,
                              void* d_out, int out_size, void* d_ws, size_t ws_size,
                              hipStream_t stream) {
  (void)in_sizes; (void)n_in; (void)out_size; (void)ws_size;
  const float* scores = (const float*)d_in[0];
  const int* labels = (const int*)d_in[1];
  float* out = (float*)d_out;
  char* ws = (char*)d_ws;
  float* col      = (float*)(ws + OFF_COL);
  float* spos     = (float*)(ws + OFF_SPOS);
  unsigned* rank  = (unsigned*)(ws + OFF_RANK);
  unsigned* hist  = (unsigned*)(ws + OFF_HIST);
  unsigned* counts= (unsigned*)(ws + OFF_CNT);
  double* accS    = (double*)(ws + OFF_ACCS);
  double* accV    = (double*)(ws + OFF_ACCV);
  double* total   = (double*)(ws + OFF_TOT);

  int zn = (int)(ZERO_BYTES / 4);
  k_zero<<<512, 256, 0, stream>>>(rank, zn);
  k_transpose<<<1024, 256, 0, stream>>>(scores, col);
  k_counts<<<64, 256, 0, stream>>>(labels, counts);
  k_posrank<<<NCLS, 256, 0, stream>>>(col, labels, spos);
  k_negrank<<<dim3(8, NCLS, 8), 256, 0, stream>>>(col, labels, rank);
  k_opt<<<dim3(64, NCLS), 256, 0, stream>>>(col, labels, counts, spos, rank, hist, accS, accV);
  k_finalize<<<NCLS, 256, 0, stream>>>(counts, hist, spos, accS, accV, total);
  k_out<<<1, 1, 0, stream>>>(total, out);
}

// Round 2
// 344.178 us; speedup vs baseline: 1.5426x; 1.5426x over previous
//
#include <hip/hip_runtime.h>
#include <stdint.h>

#define C_ITEMS 16384
#define NCLS 16
#define HSTRIDE 16386   // AP hist entries per class (opt in [1, P+1])

// ---- workspace layout (bytes) ----
static const size_t OFF_COL  = 0;                                     // 16*16384 f32 col-major scores
static const size_t OFF_SPOS = 1u << 20;                              // sorted positives (desc) per class
static const size_t OFF_RANK = 2u << 20;                              // per-(class,item) neg rank (u32)
static const size_t OFF_PACK = 3u << 20;                              // bucket-scattered (low16key,idx)
static const size_t OFF_HIST = 4u << 20;                              // 16 * HSTRIDE u32 (AP hist)
static const size_t OFF_CNT  = OFF_HIST + (size_t)NCLS * HSTRIDE * 4; // 16 u32 P-counts
static const size_t OFF_ACCS = OFF_CNT + 64;                          // 16 double
static const size_t OFF_ACCV = OFF_ACCS + 128;                        // 16 double
static const size_t OFF_TOT  = OFF_ACCV + 128;                        // 1 double
static const size_t OFF_H1   = (OFF_TOT + 8 + 255) & ~(size_t)255;    // 16 * 65536 u32 bucket hist
static const size_t ZERO_BYTES = OFF_H1 + ((size_t)NCLS << 16) * 4 - OFF_HIST;

__device__ __forceinline__ unsigned ordkey(float f) {
  unsigned b = __float_as_uint(f);
  return (b & 0x80000000u) ? ~b : (b | 0x80000000u);   // monotone float->uint
}

__global__ void k_zero(unsigned* p, int n) {
  int stride = gridDim.x * blockDim.x;
  for (int t = blockIdx.x * blockDim.x + threadIdx.x; t < n; t += stride) p[t] = 0u;
}

// transpose + per-class negative bucket histogram (65536 buckets on ordkey>>16)
__global__ void k_prep(const float* __restrict__ scores, const int* __restrict__ labels,
                       float* __restrict__ col, unsigned* __restrict__ h1) {
  int t = blockIdx.x * 256 + threadIdx.x;      // 0..262143
  float v = scores[t];
  int i = t >> 4, c = t & 15;
  col[(c << 14) | i] = v;
  if (labels[i] != c)
    atomicAdd(&h1[(c << 16) + (ordkey(v) >> 16)], 1u);
}

__global__ void k_counts(const int* __restrict__ labels, unsigned* __restrict__ counts) {
  __shared__ unsigned lc[NCLS];
  int tid = threadIdx.x;
  if (tid < NCLS) lc[tid] = 0;
  __syncthreads();
  int m = blockIdx.x * 256 + tid;
  atomicAdd(&lc[labels[m] & 15], 1u);
  __syncthreads();
  if (tid < NCLS && lc[tid]) atomicAdd(&counts[tid], lc[tid]);
}

// ---- positives: rank among positives (descending, stable) + scatter sorted array ----
#define PCAP 4096
__global__ void k_posrank(const float* __restrict__ col, const int* __restrict__ labels,
                          float* __restrict__ spos) {
  int c = blockIdx.x;
  int tid = threadIdx.x;
  const float* cs = col + (c << 14);
  __shared__ unsigned pc;
  __shared__ unsigned long long pk[PCAP];
  if (tid == 0) pc = 0;
  __syncthreads();
  for (int m = tid; m < C_ITEMS; m += 256) {
    if (labels[m] == c) {
      unsigned idx = atomicAdd(&pc, 1u);
      if (idx < PCAP)
        pk[idx] = ((unsigned long long)(~ordkey(cs[m])) << 32) | (unsigned)m;
    }
  }
  __syncthreads();
  unsigned P = pc;
  if (P <= PCAP) {
    for (unsigned q = tid; q < P; q += 256) {
      unsigned long long k64 = pk[q];
      unsigned cq = 0;
      for (unsigned t = 0; t < P; ++t) cq += (pk[t] < k64) ? 1u : 0u;
      unsigned i = (unsigned)(k64 & 0xFFFFFFFFu);
      spos[(c << 14) + cq] = cs[i];
    }
  } else { // safety fallback
    for (int m = tid; m < C_ITEMS; m += 256) {
      if (labels[m] != c) continue;
      unsigned long long k64 = ((unsigned long long)(~ordkey(cs[m])) << 32) | (unsigned)m;
      unsigned cq = 0;
      for (int t = 0; t < C_ITEMS; ++t) {
        if (labels[t] == c) {
          unsigned long long o = ((unsigned long long)(~ordkey(cs[t])) << 32) | (unsigned)t;
          cq += (o < k64) ? 1u : 0u;
        }
      }
      spos[(c << 14) + cq] = cs[m];
    }
  }
}

// ---- per-class exclusive prefix over 65536 buckets (1 block/class, 1024 thr) ----
__global__ void k_scan1(unsigned* __restrict__ h1) {
  int c = blockIdx.x;
  unsigned* h = h1 + ((size_t)c << 16);
  int tid = threadIdx.x;           // 0..1023, each owns 64 consecutive buckets
  unsigned base = (unsigned)tid << 6;
  unsigned s = 0;
  for (int q = 0; q < 64; ++q) s += h[base + q];
  __shared__ unsigned part[1024];
  part[tid] = s;
  __syncthreads();
  for (int off = 1; off < 1024; off <<= 1) {
    unsigned v = (tid >= off) ? part[tid - off] : 0u;
    __syncthreads();
    part[tid] += v;
    __syncthreads();
  }
  unsigned running = part[tid] - s;   // exclusive prefix of this thread's chunk
  for (int q = 0; q < 64; ++q) {
    unsigned tmp = h[base + q];
    h[base + q] = running;
    running += tmp;
  }
}

// ---- scatter negatives into bucket-grouped array; h1[b] becomes bucket END ----
__global__ void k_scatter(const float* __restrict__ col, const int* __restrict__ labels,
                          unsigned* __restrict__ h1, unsigned* __restrict__ pack) {
  int t = blockIdx.x * 256 + threadIdx.x;
  int c = t >> 14, i = t & 16383;
  if (labels[i] != c) {
    unsigned k = ordkey(col[t]);
    unsigned p = atomicAdd(&h1[(c << 16) + (k >> 16)], 1u);
    pack[(c << 14) + p] = (k << 16) | (unsigned)i;
  }
}

// ---- final rank: bucket start + count of smaller same-bucket entries ----
__global__ void k_rankfine(const float* __restrict__ col, const int* __restrict__ labels,
                           const unsigned* __restrict__ h1, const unsigned* __restrict__ pack,
                           unsigned* __restrict__ rank) {
  int t = blockIdx.x * 256 + threadIdx.x;
  int c = t >> 14, i = t & 16383;
  if (labels[i] != c) {
    unsigned k = ordkey(col[t]);
    unsigned b = k >> 16;
    const unsigned* hb = h1 + ((size_t)c << 16);
    unsigned start = b ? hb[b - 1] : 0u;   // after scatter: hb[x] = end of bucket x
    unsigned end = hb[b];
    unsigned mine = (k << 16) | (unsigned)i;
    const unsigned* pk = pack + (c << 14);
    unsigned cnt = start;
    for (unsigned q = start; q < end; ++q) cnt += (pk[q] < mine) ? 1u : 0u;
    rank[t] = cnt;
  }
}

// ---- per-negative suffix-scan argmax (opt_j), histogram, minus-side sums ----
#define OTILE 2048
#define HCAP 4096
__global__ void k_opt(const float* __restrict__ col, const int* __restrict__ labels,
                      const unsigned* __restrict__ counts, const float* __restrict__ spos,
                      const unsigned* __restrict__ rank, unsigned* __restrict__ hist,
                      double* __restrict__ accS, double* __restrict__ accV) {
  int c = blockIdx.y;
  int P = (int)counts[c];
  int N = C_ITEMS - P;
  if (P == 0 || N == 0) return;
  int tid = threadIdx.x;
  int i = blockIdx.x * 256 + tid;
  __shared__ float sp[OTILE];
  __shared__ unsigned lh[HCAP];
  __shared__ double red[256];
  bool active = (labels[i] != c);
  float v = col[(c << 14) + i];
  unsigned j0 = active ? rank[(c << 14) + i] : 0u;  // ascending rank, 0-based
  float invP = 1.0f / (float)P;
  float coef = 2.0f / ((float)P * (float)N);
  float a = coef * v;                               // delta = invP*rcp(j+k) - coef*sp + a
  float fcnt = (float)(j0 + (unsigned)P + 1u);      // j+k at k=P
  float s = 0.0f, best = 0.0f;
  int besti = P;
  int nchunks = (P + OTILE - 1) / OTILE;
  for (int cb = nchunks - 1; cb >= 0; --cb) {
    int base = cb * OTILE;
    int len = min(OTILE, P - base);
    __syncthreads();
    for (int t = tid; t < len; t += 256) sp[t] = spos[(c << 14) + base + t];
    __syncthreads();
    if (active) {
      for (int q = len - 1; q >= 0; --q) {
        float spv = sp[q];
        float r = __builtin_amdgcn_rcpf(fcnt);
        float delta = fmaf(invP, r, fmaf(-coef, spv, a));
        s += delta;
        if (s >= best) { best = s; besti = base + q; }  // >= : first-max-on-tie
        fcnt -= 1.0f;
      }
    }
  }
  int opt = besti + 1;  // 1..P+1
  if (P + 2 <= HCAP) {
    __syncthreads();
    for (int t = tid; t < P + 2; t += 256) lh[t] = 0u;
    __syncthreads();
    if (active) atomicAdd(&lh[opt], 1u);
    __syncthreads();
    for (int t = tid; t < P + 2; t += 256)
      if (lh[t]) atomicAdd(&hist[c * HSTRIDE + t], lh[t]);
  } else {
    if (active) atomicAdd(&hist[c * HSTRIDE + opt], 1u);
  }
  double cm = active ? (double)(P + 2 - 2 * opt) * (double)v : 0.0;
  double sv = active ? (double)v : 0.0;
  red[tid] = cm; __syncthreads();
  for (int sh = 128; sh > 0; sh >>= 1) { if (tid < sh) red[tid] += red[tid + sh]; __syncthreads(); }
  if (tid == 0) atomicAdd(&accS[c], red[0]);
  __syncthreads();
  red[tid] = sv; __syncthreads();
  for (int sh = 128; sh > 0; sh >>= 1) { if (tid < sh) red[tid] += red[tid + sh]; __syncthreads(); }
  if (tid == 0) atomicAdd(&accV[c], red[0]);
}

// ---- per-class: prefix-sum hist -> r_plus, plus-side sums, loss ----
__global__ void k_finalize(const unsigned* __restrict__ counts, const unsigned* __restrict__ hist,
                           const float* __restrict__ spos, const double* __restrict__ accS,
                           const double* __restrict__ accV, double* __restrict__ total) {
  int c = blockIdx.x;
  int tid = threadIdx.x;
  int P = (int)counts[c];
  int N = C_ITEMS - P;
  if (P == 0 || N == 0) return;
  __shared__ unsigned sc[256];
  __shared__ double red[256];
  const unsigned* h = hist + c * HSTRIDE;
  int M = P + 1;
  int L = (M + 255) / 256;
  int o0 = 1 + tid * L;
  int o1 = min(o0 + L, P + 2);
  unsigned part = 0;
  for (int o = o0; o < o1; ++o) part += h[o];
  sc[tid] = part;
  __syncthreads();
  if (tid == 0) {
    unsigned runp = 0;
    for (int t = 0; t < 256; ++t) { unsigned tmp = sc[t]; sc[t] = runp; runp += tmp; }
  }
  __syncthreads();
  unsigned run = sc[tid];
  double a1 = 0.0, a2 = 0.0, a3 = 0.0;
  for (int o = o0; o < o1; ++o) {
    run += h[o];
    if (o <= P) {
      int k0 = o - 1;
      double rp = 1.0 + (double)run;
      double spv = (double)spos[(c << 14) + k0];
      a1 += (double)(k0 + 1) / ((double)k0 + rp);
      a2 += spv * ((double)N + 2.0 - 2.0 * rp);
      a3 += spv;
    }
  }
  red[tid] = a1; __syncthreads();
  for (int s = 128; s > 0; s >>= 1) { if (tid < s) red[tid] += red[tid + s]; __syncthreads(); }
  double r1 = red[0]; __syncthreads();
  red[tid] = a2; __syncthreads();
  for (int s = 128; s > 0; s >>= 1) { if (tid < s) red[tid] += red[tid + s]; __syncthreads(); }
  double r2 = red[0]; __syncthreads();
  red[tid] = a3; __syncthreads();
  for (int s = 128; s > 0; s >>= 1) { if (tid < s) red[tid] += red[tid + s]; __syncthreads(); }
  double r3 = red[0];
  if (tid == 0) {
    double Pd = (double)P, Nd = (double)N;
    double FR  = r2 + accS[c];
    double FRs = Nd * r3 - Pd * accV[c];
    double lc  = (1.0 - r1 / Pd) + (FR - FRs) / (Pd * Nd);
    atomicAdd(total, lc);
  }
}

__global__ void k_out(const double* __restrict__ total, float* __restrict__ out) {
  out[0] = (float)(total[0] / (double)NCLS);
}

extern "C" void kernel_launch(void* const* d_in, const int* in_sizes, int n_in,
                              void* d_out, int out_size, void* d_ws, size_t ws_size,
                              hipStream_t stream) {
  (void)in_sizes; (void)n_in; (void)out_size; (void)ws_size;
  const float* scores = (const float*)d_in[0];
  const int* labels = (const int*)d_in[1];
  float* out = (float*)d_out;
  char* ws = (char*)d_ws;
  float* col      = (float*)(ws + OFF_COL);
  float* spos     = (float*)(ws + OFF_SPOS);
  unsigned* rank  = (unsigned*)(ws + OFF_RANK);
  unsigned* pack  = (unsigned*)(ws + OFF_PACK);
  unsigned* hist  = (unsigned*)(ws + OFF_HIST);
  unsigned* counts= (unsigned*)(ws + OFF_CNT);
  double* accS    = (double*)(ws + OFF_ACCS);
  double* accV    = (double*)(ws + OFF_ACCV);
  double* total   = (double*)(ws + OFF_TOT);
  unsigned* h1    = (unsigned*)(ws + OFF_H1);

  int zn = (int)(ZERO_BYTES / 4);
  k_zero<<<1024, 256, 0, stream>>>(hist, zn);               // zeroes hist..h1 (contiguous)
  k_prep<<<1024, 256, 0, stream>>>(scores, labels, col, h1);
  k_counts<<<64, 256, 0, stream>>>(labels, counts);
  k_posrank<<<NCLS, 256, 0, stream>>>(col, labels, spos);
  k_scan1<<<NCLS, 1024, 0, stream>>>(h1);
  k_scatter<<<1024, 256, 0, stream>>>(col, labels, h1, pack);
  k_rankfine<<<1024, 256, 0, stream>>>(col, labels, h1, pack, rank);
  k_opt<<<dim3(64, NCLS), 256, 0, stream>>>(col, labels, counts, spos, rank, hist, accS, accV);
  k_finalize<<<NCLS, 256, 0, stream>>>(counts, hist, spos, accS, accV, total);
  k_out<<<1, 1, 0, stream>>>(total, out);
}

// Round 3
// 298.509 us; speedup vs baseline: 1.7786x; 1.1530x over previous
//
#include <hip/hip_runtime.h>
#include <stdint.h>

#define C_ITEMS 16384
#define NCLS 16
#define HSTRIDE 16386   // AP hist entries per class (opt in [1, P+1])

// ---- workspace layout (bytes) ----
static const size_t OFF_COL  = 0;                                     // 16*16384 f32 col-major scores
static const size_t OFF_SPOS = 1u << 20;                              // sorted positives (desc) per class
static const size_t OFF_RANK = 2u << 20;                              // per-(class,item) neg rank (u32)
static const size_t OFF_PACK = 3u << 20;                              // bucket-scattered (low16key,idx)
static const size_t OFF_HIST = 4u << 20;                              // 16 * HSTRIDE u32 (AP hist)
static const size_t OFF_CNT  = OFF_HIST + (size_t)NCLS * HSTRIDE * 4; // 16 u32 P-counts
static const size_t OFF_ACCS = OFF_CNT + 64;                          // 16 double
static const size_t OFF_ACCV = OFF_ACCS + 128;                        // 16 double
static const size_t OFF_TOT  = OFF_ACCV + 128;                        // 1 double
static const size_t OFF_PC   = OFF_TOT + 8;                           // 16 u32 positive-collect counters
static const size_t OFF_H1   = (OFF_PC + 64 + 255) & ~(size_t)255;    // 16 * 65536 u32 bucket hist
static const size_t OFF_PPK  = OFF_H1 + (((size_t)NCLS << 16) * 4);   // 16 * 16384 u64 positive keys
static const size_t ZERO_BYTES = OFF_PPK - OFF_HIST;                  // zero hist..h1 end

__device__ __forceinline__ unsigned ordkey(float f) {
  unsigned b = __float_as_uint(f);
  return (b & 0x80000000u) ? ~b : (b | 0x80000000u);   // monotone float->uint
}

__global__ void k_zero(unsigned* p, int n) {
  int stride = gridDim.x * blockDim.x;
  for (int t = blockIdx.x * blockDim.x + threadIdx.x; t < n; t += stride) p[t] = 0u;
}

// transpose + per-class negative bucket histogram (65536 buckets on ordkey>>16)
__global__ void k_prep(const float* __restrict__ scores, const int* __restrict__ labels,
                       float* __restrict__ col, unsigned* __restrict__ h1) {
  int t = blockIdx.x * 256 + threadIdx.x;      // 0..262143
  float v = scores[t];
  int i = t >> 4, c = t & 15;
  col[(c << 14) | i] = v;
  if (labels[i] != c)
    atomicAdd(&h1[(c << 16) + (ordkey(v) >> 16)], 1u);
}

__global__ void k_counts(const int* __restrict__ labels, unsigned* __restrict__ counts) {
  __shared__ unsigned lc[NCLS];
  int tid = threadIdx.x;
  if (tid < NCLS) lc[tid] = 0;
  __syncthreads();
  int m = blockIdx.x * 256 + tid;
  atomicAdd(&lc[labels[m] & 15], 1u);
  __syncthreads();
  if (tid < NCLS && lc[tid]) atomicAdd(&counts[tid], lc[tid]);
}

// ---- positives: collect (key,idx) per class into global lists ----
__global__ void k_poscollect(const float* __restrict__ scores, const int* __restrict__ labels,
                             unsigned* __restrict__ pcnt, unsigned long long* __restrict__ ppk) {
  int i = blockIdx.x * 256 + threadIdx.x;   // 0..16383
  int c = labels[i] & 15;
  float v = scores[i * NCLS + c];
  unsigned idx = atomicAdd(&pcnt[c], 1u);
  ppk[(c << 14) + idx] = ((unsigned long long)(~ordkey(v)) << 32) | (unsigned)i;
}

// ---- positives: rank (descending, stable-equivalent) + scatter sorted values ----
#define PCAP 4096
__global__ void k_posrank2(const float* __restrict__ scores,
                           const unsigned long long* __restrict__ ppk,
                           const unsigned* __restrict__ pcnt, float* __restrict__ spos) {
  int c = blockIdx.y;
  unsigned P = pcnt[c];
  int tid = threadIdx.x;
  __shared__ unsigned long long pk[PCAP];
  const unsigned long long* src = ppk + ((size_t)c << 14);
  if (P <= PCAP) {
    for (unsigned t = tid; t < P; t += 256) pk[t] = src[t];
    __syncthreads();
    for (unsigned q = blockIdx.x * 256 + tid; q < P; q += gridDim.x * 256) {
      unsigned long long k64 = pk[q];
      unsigned cq = 0;
      for (unsigned t = 0; t < P; ++t) cq += (pk[t] < k64) ? 1u : 0u;
      unsigned i = (unsigned)(k64 & 0xFFFFFFFFu);
      spos[(c << 14) + cq] = scores[i * NCLS + c];
    }
  } else { // safety fallback: global-memory version (won't trigger for this input)
    for (unsigned q = blockIdx.x * 256 + tid; q < P; q += gridDim.x * 256) {
      unsigned long long k64 = src[q];
      unsigned cq = 0;
      for (unsigned t = 0; t < P; ++t) cq += (src[t] < k64) ? 1u : 0u;
      unsigned i = (unsigned)(k64 & 0xFFFFFFFFu);
      spos[(c << 14) + cq] = scores[i * NCLS + c];
    }
  }
}

// ---- per-class exclusive prefix over 65536 buckets (1 block/class, 1024 thr) ----
__global__ void k_scan1(unsigned* __restrict__ h1) {
  int c = blockIdx.x;
  unsigned* h = h1 + ((size_t)c << 16);
  int tid = threadIdx.x;           // 0..1023, each owns 64 consecutive buckets
  unsigned base = (unsigned)tid << 6;
  unsigned s = 0;
  for (int q = 0; q < 64; ++q) s += h[base + q];
  __shared__ unsigned part[1024];
  part[tid] = s;
  __syncthreads();
  for (int off = 1; off < 1024; off <<= 1) {
    unsigned v = (tid >= off) ? part[tid - off] : 0u;
    __syncthreads();
    part[tid] += v;
    __syncthreads();
  }
  unsigned running = part[tid] - s;   // exclusive prefix of this thread's chunk
  for (int q = 0; q < 64; ++q) {
    unsigned tmp = h[base + q];
    h[base + q] = running;
    running += tmp;
  }
}

// ---- scatter negatives into bucket-grouped array; h1[b] becomes bucket END ----
__global__ void k_scatter(const float* __restrict__ col, const int* __restrict__ labels,
                          unsigned* __restrict__ h1, unsigned* __restrict__ pack) {
  int t = blockIdx.x * 256 + threadIdx.x;
  int c = t >> 14, i = t & 16383;
  if (labels[i] != c) {
    unsigned k = ordkey(col[t]);
    unsigned p = atomicAdd(&h1[(c << 16) + (k >> 16)], 1u);
    pack[(c << 14) + p] = (k << 16) | (unsigned)i;
  }
}

// ---- final rank: bucket start + count of smaller same-bucket entries ----
__global__ void k_rankfine(const float* __restrict__ col, const int* __restrict__ labels,
                           const unsigned* __restrict__ h1, const unsigned* __restrict__ pack,
                           unsigned* __restrict__ rank) {
  int t = blockIdx.x * 256 + threadIdx.x;
  int c = t >> 14, i = t & 16383;
  if (labels[i] != c) {
    unsigned k = ordkey(col[t]);
    unsigned b = k >> 16;
    const unsigned* hb = h1 + ((size_t)c << 16);
    unsigned start = b ? hb[b - 1] : 0u;   // after scatter: hb[x] = end of bucket x
    unsigned end = hb[b];
    unsigned mine = (k << 16) | (unsigned)i;
    const unsigned* pk = pack + (c << 14);
    unsigned cnt = start;
    for (unsigned q = start; q < end; ++q) cnt += (pk[q] < mine) ? 1u : 0u;
    rank[t] = cnt;
  }
}

// ---- per-negative suffix-scan argmax (opt_j), histogram, minus-side sums ----
#define OTILE 2048
#define HCAP 4096
__global__ void k_opt(const float* __restrict__ col, const int* __restrict__ labels,
                      const unsigned* __restrict__ counts, const float* __restrict__ spos,
                      const unsigned* __restrict__ rank, unsigned* __restrict__ hist,
                      double* __restrict__ accS, double* __restrict__ accV) {
  int c = blockIdx.y;
  int P = (int)counts[c];
  int N = C_ITEMS - P;
  if (P == 0 || N == 0) return;
  int tid = threadIdx.x;
  int i = blockIdx.x * 256 + tid;
  __shared__ float sp[OTILE];
  __shared__ unsigned lh[HCAP];
  __shared__ double red[256];
  bool active = (labels[i] != c);
  float v = col[(c << 14) + i];
  unsigned j0 = active ? rank[(c << 14) + i] : 0u;  // ascending rank, 0-based
  float invP = 1.0f / (float)P;
  float coef = 2.0f / ((float)P * (float)N);
  float a = coef * v;                               // delta = invP*rcp(j+k) - coef*sp + a
  float fcnt = (float)(j0 + (unsigned)P + 1u);      // j+k at k=P
  float s = 0.0f, best = 0.0f;
  int besti = P;
  int nchunks = (P + OTILE - 1) / OTILE;
  for (int cb = nchunks - 1; cb >= 0; --cb) {
    int base = cb * OTILE;
    int len = min(OTILE, P - base);
    __syncthreads();
    for (int t = tid; t < len; t += 256) sp[t] = spos[(c << 14) + base + t];
    __syncthreads();
    if (active) {
      for (int q = len - 1; q >= 0; --q) {
        float spv = sp[q];
        float r = __builtin_amdgcn_rcpf(fcnt);
        float delta = fmaf(invP, r, fmaf(-coef, spv, a));
        s += delta;
        if (s >= best) { best = s; besti = base + q; }  // >= : first-max-on-tie
        fcnt -= 1.0f;
      }
    }
  }
  int opt = besti + 1;  // 1..P+1
  if (P + 2 <= HCAP) {
    __syncthreads();
    for (int t = tid; t < P + 2; t += 256) lh[t] = 0u;
    __syncthreads();
    if (active) atomicAdd(&lh[opt], 1u);
    __syncthreads();
    for (int t = tid; t < P + 2; t += 256)
      if (lh[t]) atomicAdd(&hist[c * HSTRIDE + t], lh[t]);
  } else {
    if (active) atomicAdd(&hist[c * HSTRIDE + opt], 1u);
  }
  double cm = active ? (double)(P + 2 - 2 * opt) * (double)v : 0.0;
  double sv = active ? (double)v : 0.0;
  red[tid] = cm; __syncthreads();
  for (int sh = 128; sh > 0; sh >>= 1) { if (tid < sh) red[tid] += red[tid + sh]; __syncthreads(); }
  if (tid == 0) atomicAdd(&accS[c], red[0]);
  __syncthreads();
  red[tid] = sv; __syncthreads();
  for (int sh = 128; sh > 0; sh >>= 1) { if (tid < sh) red[tid] += red[tid + sh]; __syncthreads(); }
  if (tid == 0) atomicAdd(&accV[c], red[0]);
}

// ---- per-class: prefix-sum hist -> r_plus, plus-side sums, loss ----
__global__ void k_finalize(const unsigned* __restrict__ counts, const unsigned* __restrict__ hist,
                           const float* __restrict__ spos, const double* __restrict__ accS,
                           const double* __restrict__ accV, double* __restrict__ total) {
  int c = blockIdx.x;
  int tid = threadIdx.x;
  int P = (int)counts[c];
  int N = C_ITEMS - P;
  if (P == 0 || N == 0) return;
  __shared__ unsigned sc[256];
  __shared__ double red[256];
  const unsigned* h = hist + c * HSTRIDE;
  int M = P + 1;
  int L = (M + 255) / 256;
  int o0 = 1 + tid * L;
  int o1 = min(o0 + L, P + 2);
  unsigned part = 0;
  for (int o = o0; o < o1; ++o) part += h[o];
  sc[tid] = part;
  __syncthreads();
  if (tid == 0) {
    unsigned runp = 0;
    for (int t = 0; t < 256; ++t) { unsigned tmp = sc[t]; sc[t] = runp; runp += tmp; }
  }
  __syncthreads();
  unsigned run = sc[tid];
  double a1 = 0.0, a2 = 0.0, a3 = 0.0;
  for (int o = o0; o < o1; ++o) {
    run += h[o];
    if (o <= P) {
      int k0 = o - 1;
      double rp = 1.0 + (double)run;
      double spv = (double)spos[(c << 14) + k0];
      a1 += (double)(k0 + 1) / ((double)k0 + rp);
      a2 += spv * ((double)N + 2.0 - 2.0 * rp);
      a3 += spv;
    }
  }
  red[tid] = a1; __syncthreads();
  for (int s = 128; s > 0; s >>= 1) { if (tid < s) red[tid] += red[tid + s]; __syncthreads(); }
  double r1 = red[0]; __syncthreads();
  red[tid] = a2; __syncthreads();
  for (int s = 128; s > 0; s >>= 1) { if (tid < s) red[tid] += red[tid + s]; __syncthreads(); }
  double r2 = red[0]; __syncthreads();
  red[tid] = a3; __syncthreads();
  for (int s = 128; s > 0; s >>= 1) { if (tid < s) red[tid] += red[tid + s]; __syncthreads(); }
  double r3 = red[0];
  if (tid == 0) {
    double Pd = (double)P, Nd = (double)N;
    double FR  = r2 + accS[c];
    double FRs = Nd * r3 - Pd * accV[c];
    double lc  = (1.0 - r1 / Pd) + (FR - FRs) / (Pd * Nd);
    atomicAdd(total, lc);
  }
}

__global__ void k_out(const double* __restrict__ total, float* __restrict__ out) {
  out[0] = (float)(total[0] / (double)NCLS);
}

extern "C" void kernel_launch(void* const* d_in, const int* in_sizes, int n_in,
                              void* d_out, int out_size, void* d_ws, size_t ws_size,
                              hipStream_t stream) {
  (void)in_sizes; (void)n_in; (void)out_size; (void)ws_size;
  const float* scores = (const float*)d_in[0];
  const int* labels = (const int*)d_in[1];
  float* out = (float*)d_out;
  char* ws = (char*)d_ws;
  float* col      = (float*)(ws + OFF_COL);
  float* spos     = (float*)(ws + OFF_SPOS);
  unsigned* rank  = (unsigned*)(ws + OFF_RANK);
  unsigned* pack  = (unsigned*)(ws + OFF_PACK);
  unsigned* hist  = (unsigned*)(ws + OFF_HIST);
  unsigned* counts= (unsigned*)(ws + OFF_CNT);
  double* accS    = (double*)(ws + OFF_ACCS);
  double* accV    = (double*)(ws + OFF_ACCV);
  double* total   = (double*)(ws + OFF_TOT);
  unsigned* pcnt  = (unsigned*)(ws + OFF_PC);
  unsigned* h1    = (unsigned*)(ws + OFF_H1);
  unsigned long long* ppk = (unsigned long long*)(ws + OFF_PPK);

  int zn = (int)(ZERO_BYTES / 4);
  k_zero<<<1024, 256, 0, stream>>>(hist, zn);               // zeroes hist..h1 (contiguous)
  k_prep<<<1024, 256, 0, stream>>>(scores, labels, col, h1);
  k_counts<<<64, 256, 0, stream>>>(labels, counts);
  k_poscollect<<<64, 256, 0, stream>>>(scores, labels, pcnt, ppk);
  k_posrank2<<<dim3(16, NCLS), 256, 0, stream>>>(scores, ppk, pcnt, spos);
  k_scan1<<<NCLS, 1024, 0, stream>>>(h1);
  k_scatter<<<1024, 256, 0, stream>>>(col, labels, h1, pack);
  k_rankfine<<<1024, 256, 0, stream>>>(col, labels, h1, pack, rank);
  k_opt<<<dim3(64, NCLS), 256, 0, stream>>>(col, labels, counts, spos, rank, hist, accS, accV);
  k_finalize<<<NCLS, 256, 0, stream>>>(counts, hist, spos, accS, accV, total);
  k_out<<<1, 1, 0, stream>>>(total, out);
}